// Round 12
// baseline (516.275 us; speedup 1.0000x reference)
//
#include <hip/hip_runtime.h>

typedef unsigned short u16;
typedef unsigned int u32;
typedef unsigned long long u64;

#define N_NODES 100000
#define N_EDGES 1600000
#define TPITCH 136   // LDS pitch (u16): 272B rows, 16B-aligned
#define NBIN 196     // ceil(N_NODES/512)
#define BCAP 12288   // per-bin pair capacity
#define NPART 512    // radix partition blocks
#define EPB 3125     // edges per partition

typedef __bf16 bf16x8 __attribute__((ext_vector_type(8)));
typedef float  f32x4  __attribute__((ext_vector_type(4)));

__device__ inline float b2f(u16 b) { return __uint_as_float(((u32)b) << 16); }
__device__ inline float b2f_lo(u32 u) { return __uint_as_float(u << 16); }
__device__ inline float b2f_hi(u32 u) { return __uint_as_float(u & 0xffff0000u); }
__device__ inline u16 f2b(float f) {  // RNE float->bf16
    u32 u = __float_as_uint(f);
    return (u16)((u + 0x7fffu + ((u >> 16) & 1u)) >> 16);
}

__device__ inline bf16x8 ldfrag(const u16* base, int row, int k) {
    union { uint4 u; bf16x8 v; } t;
    t.u = *(const uint4*)(base + (size_t)row * 128 + k);
    return t.v;
}
__device__ inline bf16x8 ldfrag_f32(const float* base, int row, int k) {
    const float4* p = (const float4*)(base + (size_t)row * 128 + k);
    float4 a = p[0], b = p[1];
    union { u16 h[8]; bf16x8 v; } t;
    t.h[0] = f2b(a.x); t.h[1] = f2b(a.y); t.h[2] = f2b(a.z); t.h[3] = f2b(a.w);
    t.h[4] = f2b(b.x); t.h[5] = f2b(b.y); t.h[6] = f2b(b.z); t.h[7] = f2b(b.w);
    return t.v;
}
__device__ inline bf16x8 ldfrag_lds(const u16* tile, int lrow, int k) {
    union { uint4 u; bf16x8 v; } t;
    t.u = *(const uint4*)(tile + lrow * TPITCH + k);
    return t.v;
}
__device__ inline f32x4 mfma16(bf16x8 a, bf16x8 b, f32x4 c) {
    return __builtin_amdgcn_mfma_f32_16x16x32_bf16(a, b, c, 0, 0, 0);
}

// cooperative stage: 128x128 bf16 = 2048 16B chunks; 256 thr x 8 iters
__device__ inline void stage_w(const u16* __restrict__ g, u16* lds) {
    int t = threadIdx.x;
#pragma unroll
    for (int i = 0; i < 8; i++) {
        int u = t + i * 256;
        int row = u >> 4, k = (u & 15) * 8;
        *(uint4*)(lds + row * TPITCH + k) = *(const uint4*)(g + row * 128 + k);
    }
}

// ---- diagnostic ----
__global__ __launch_bounds__(256) void k_diag(u16* __restrict__ out, float val) {
    int i = blockIdx.x * 256 + threadIdx.x;
    if (i < N_NODES) out[i] = f2b(val);
}

// ---- combined detect ----
__global__ __launch_bounds__(256) void k_detects(const u64* __restrict__ e,
                                                 const u32* __restrict__ x,
                                                 int* __restrict__ flags) {
    int t = threadIdx.x;
    if (blockIdx.x == 0) {
        u64 v = 0;
#pragma unroll
        for (int i = 0; i < 4; i++) v |= e[t + 256 * i];
        if (v >> 32) atomicOr(&flags[0], 1);
    } else {
        int bad = 0;
#pragma unroll
        for (int i = 0; i < 4; i++) {
            u32 w = x[t + 256 * i];
            u32 ex = (w >> 7) & 0xff;
            if (ex < 100 || ex > 140) bad = 1;
        }
        if (bad) atomicOr(&flags[1], 1);
    }
}

__device__ inline void load_edge(const int* ei, int is32, int e, int& src, int& dst) {
    if (is32) {
        src = ei[e]; dst = ei[N_EDGES + e];
    } else {
        const long long* e64 = (const long long*)ei;
        src = (int)e64[e]; dst = (int)e64[N_EDGES + e];
    }
}

// ---- radix partition build (proven R9/R11) ----
__global__ __launch_bounds__(256) void k_rhist(const int* __restrict__ ei,
                                               int* __restrict__ ghist,
                                               const int* __restrict__ flags) {
    __shared__ int hist[NBIN];
    int p = blockIdx.x, t = threadIdx.x;
    for (int i = t; i < NBIN; i += 256) hist[i] = 0;
    __syncthreads();
    int is32 = flags[0];
    int base = p * EPB;
    int end = base + EPB; if (end > N_EDGES) end = N_EDGES;
    for (int e = base + t; e < end; e += 256) {
        int src, dst; load_edge(ei, is32, e, src, dst);
        if ((u32)src < N_NODES && (u32)dst < N_NODES) atomicAdd(&hist[dst >> 9], 1);
    }
    __syncthreads();
    for (int i = t; i < NBIN; i += 256) ghist[i * NPART + p] = hist[i];
}
__global__ __launch_bounds__(512) void k_rscan(const int* __restrict__ ghist,
                                               int* __restrict__ gbase,
                                               int* __restrict__ gcur) {
    __shared__ int buf[NPART];
    int b = blockIdx.x, t = threadIdx.x;
    int v = ghist[b * NPART + t];
    buf[t] = v;
    __syncthreads();
    for (int s = 1; s < NPART; s <<= 1) {
        int a = (t >= s) ? buf[t - s] : 0;
        __syncthreads();
        buf[t] += a;
        __syncthreads();
    }
    gbase[b * NPART + t] = buf[t] - v;
    if (t == NPART - 1) gcur[b] = buf[t];
}
__global__ __launch_bounds__(256) void k_rscatter(const int* __restrict__ ei,
                                                  const int* __restrict__ gbase,
                                                  u32* __restrict__ gbuf,
                                                  const int* __restrict__ flags) {
    __shared__ int cur[NBIN];
    int p = blockIdx.x, t = threadIdx.x;
    for (int i = t; i < NBIN; i += 256) cur[i] = gbase[i * NPART + p];
    __syncthreads();
    int is32 = flags[0];
    int base = p * EPB;
    int end = base + EPB; if (end > N_EDGES) end = N_EDGES;
    for (int e = base + t; e < end; e += 256) {
        int src, dst; load_edge(ei, is32, e, src, dst);
        if ((u32)src < N_NODES && (u32)dst < N_NODES) {
            int bin = dst >> 9;
            int pos = atomicAdd(&cur[bin], 1);
            if (pos < BCAP)
                gbuf[(size_t)bin * BCAP + pos] = ((u32)(dst & 511) << 17) | (u32)src;
        }
    }
}
__global__ __launch_bounds__(512) void k_binB(const int* __restrict__ gcur,
                                              const u32* __restrict__ gbuf,
                                              u32* __restrict__ csr,
                                              int* __restrict__ cnt,
                                              int* __restrict__ offN) {
    __shared__ int hist[512];
    __shared__ int pfx[512];
    __shared__ int cur[512];
    __shared__ u32 srcbuf[BCAP];
    int b = blockIdx.x, t = threadIdx.x;
    int n = gcur[b]; if (n > BCAP) n = BCAP;
    hist[t] = 0;
    __syncthreads();
    for (int i = t; i < n; i += 512)
        atomicAdd(&hist[gbuf[(size_t)b * BCAP + i] >> 17], 1);
    __syncthreads();
    pfx[t] = hist[t];
    __syncthreads();
    for (int s = 1; s < 512; s <<= 1) {
        int a = (t >= s) ? pfx[t - s] : 0;
        __syncthreads();
        pfx[t] += a;
        __syncthreads();
    }
    int excl = pfx[t] - hist[t];
    cur[t] = excl;
    __syncthreads();
    for (int i = t; i < n; i += 512) {
        u32 p = gbuf[(size_t)b * BCAP + i];
        int pos = atomicAdd(&cur[p >> 17], 1);
        if (pos < BCAP) srcbuf[pos] = p & 0x1FFFFu;
    }
    __syncthreads();
    int total = pfx[511];
    for (int i = t; i < total; i += 512)
        csr[(size_t)b * BCAP + i] = srcbuf[i];
    int node = b * 512 + t;
    if (node < N_NODES) {
        cnt[node] = hist[t];
        offN[node] = b * BCAP + excl;
    }
}

// ---- weight normalization -> bf16 ----
#define WTOT 99073
struct CvtArgs { const void* src[10]; int off[10]; int n[10]; };
__global__ __launch_bounds__(256) void k_cvtw(CvtArgs a, u16* __restrict__ dst,
                                              const int* __restrict__ flags) {
    int i = blockIdx.x * 256 + threadIdx.x;
    if (i >= WTOT) return;
    int isf = flags[1];
    int s = 0;
    while (s < 9 && i >= a.off[s + 1]) s++;
    int j = i - a.off[s];
    float v = isf ? ((const float*)a.src[s])[j] : b2f(((const u16*)a.src[s])[j]);
    dst[i] = f2b(v);
}
#define W_W1L 0
#define W_W1R 16384
#define W_W2L 32768
#define W_W2R 49152
#define W_W3  65536
#define W_W4  98304
#define W_B1  98560
#define W_B2  98688
#define W_B3  98816
#define W_B4  99072

// ---- x -> bf16 convert ----
__global__ __launch_bounds__(256) void k_cvtx(const void* __restrict__ x,
                                              u16* __restrict__ xb,
                                              const int* __restrict__ flags) {
    int i = blockIdx.x * 256 + threadIdx.x;
    if ((size_t)i * 4 >= (size_t)N_NODES * 128) return;
    if (flags[1]) {
        float4 v = ((const float4*)x)[i];
        union { u16 h[4]; u64 q; } t;
        t.h[0] = f2b(v.x); t.h[1] = f2b(v.y); t.h[2] = f2b(v.z); t.h[3] = f2b(v.w);
        ((u64*)xb)[i] = t.q;
    } else {
        ((u64*)xb)[i] = ((const u64*)x)[i];
    }
}

// ---- wave-private agg of 16 rows into LDS tile (bf16 features, 4-deep ILP) ----
__device__ inline void agg16_bf16(const u16* __restrict__ feat,
                                  const int* __restrict__ cnt,
                                  const int* __restrict__ offN,
                                  const u32* __restrict__ csr,
                                  u16* tile, int rb, int wid, int lane) {
    const u32* f = (const u32*)feat;
    for (int rr = 0; rr < 16; rr++) {
        int node = rb + wid * 16 + rr;
        float a0 = 0, a1 = 0, b0 = 0, b1 = 0, c0 = 0, c1 = 0, d0 = 0, d1 = 0;
        int deg = 0;
        if (node < N_NODES) {
            deg = cnt[node];
            int s = offN[node];
            int p = 0;
            for (; p + 3 < deg; p += 4) {
                u32 n0 = csr[s + p], n1 = csr[s + p + 1], n2 = csr[s + p + 2], n3 = csr[s + p + 3];
                if (n0 >= N_NODES) n0 = 0;
                if (n1 >= N_NODES) n1 = 0;
                if (n2 >= N_NODES) n2 = 0;
                if (n3 >= N_NODES) n3 = 0;
                u32 w0 = f[(size_t)n0 * 64 + lane];
                u32 w1 = f[(size_t)n1 * 64 + lane];
                u32 w2 = f[(size_t)n2 * 64 + lane];
                u32 w3 = f[(size_t)n3 * 64 + lane];
                a0 += b2f_lo(w0); a1 += b2f_hi(w0);
                b0 += b2f_lo(w1); b1 += b2f_hi(w1);
                c0 += b2f_lo(w2); c1 += b2f_hi(w2);
                d0 += b2f_lo(w3); d1 += b2f_hi(w3);
            }
            for (; p < deg; p++) {
                u32 n0 = csr[s + p];
                if (n0 >= N_NODES) n0 = 0;
                u32 w0 = f[(size_t)n0 * 64 + lane];
                a0 += b2f_lo(w0); a1 += b2f_hi(w0);
            }
        }
        float s0 = (a0 + b0) + (c0 + d0), s1 = (a1 + b1) + (c1 + d1);
        float sc = deg > 0 ? 1.f / (float)deg : 0.f;
        u16 h0 = f2b(s0 * sc), h1 = f2b(s1 * sc);
        ((u32*)tile)[(wid * 16 + rr) * (TPITCH / 2) + lane] = (u32)h0 | ((u32)h1 << 16);
    }
}

// dual-dtype raw-x variant (T1 fallback)
__device__ inline void agg16_x(const void* __restrict__ x, int isf,
                               const int* __restrict__ cnt,
                               const int* __restrict__ offN,
                               const u32* __restrict__ csr,
                               u16* tile, int rb, int wid, int lane) {
    for (int rr = 0; rr < 16; rr++) {
        int node = rb + wid * 16 + rr;
        float a0 = 0, a1 = 0, b0 = 0, b1 = 0;
        int deg = 0;
        if (node < N_NODES) {
            deg = cnt[node];
            int s = offN[node];
            int p = 0;
            if (isf) {
                const float2* f = (const float2*)x;
                for (; p + 1 < deg; p += 2) {
                    u32 n0 = csr[s + p], n1 = csr[s + p + 1];
                    if (n0 >= N_NODES) n0 = 0;
                    if (n1 >= N_NODES) n1 = 0;
                    float2 w0 = f[(size_t)n0 * 64 + lane];
                    float2 w1 = f[(size_t)n1 * 64 + lane];
                    a0 += w0.x; a1 += w0.y; b0 += w1.x; b1 += w1.y;
                }
                for (; p < deg; p++) {
                    u32 n0 = csr[s + p];
                    if (n0 >= N_NODES) n0 = 0;
                    float2 w0 = f[(size_t)n0 * 64 + lane];
                    a0 += w0.x; a1 += w0.y;
                }
            } else {
                const u32* f = (const u32*)x;
                for (; p + 1 < deg; p += 2) {
                    u32 n0 = csr[s + p], n1 = csr[s + p + 1];
                    if (n0 >= N_NODES) n0 = 0;
                    if (n1 >= N_NODES) n1 = 0;
                    u32 w0 = f[(size_t)n0 * 64 + lane];
                    u32 w1 = f[(size_t)n1 * 64 + lane];
                    a0 += b2f_lo(w0); a1 += b2f_hi(w0);
                    b0 += b2f_lo(w1); b1 += b2f_hi(w1);
                }
                for (; p < deg; p++) {
                    u32 n0 = csr[s + p];
                    if (n0 >= N_NODES) n0 = 0;
                    u32 w0 = f[(size_t)n0 * 64 + lane];
                    a0 += b2f_lo(w0); a1 += b2f_hi(w0);
                }
            }
        }
        float s0 = a0 + b0, s1 = a1 + b1;
        float sc = deg > 0 ? 1.f / (float)deg : 0.f;
        u16 h0 = f2b(s0 * sc), h1 = f2b(s1 * sc);
        ((u32*)tile)[(wid * 16 + rr) * (TPITCH / 2) + lane] = (u32)h0 | ((u32)h1 << 16);
    }
}

// ---- fused conv1: agg(x)->tile (wave-private rows); h1 = relu(agg@W1l^T + b1 + x@W1r^T) ----
template <bool DUALX>
__global__ __launch_bounds__(256) void k_fconv1(
    const void* __restrict__ xself, const int* __restrict__ cnt,
    const int* __restrict__ offN, const u32* __restrict__ csrb,
    const u16* __restrict__ Wc, const int* __restrict__ flags,
    u16* __restrict__ h1) {
    __shared__ __align__(16) u16 wbuf[128 * TPITCH];  // 34.8 KB
    __shared__ __align__(16) u16 tile[64 * TPITCH];   // 17.4 KB -> 3 blocks/CU
    int wid = threadIdx.x >> 6, lane = threadIdx.x & 63;
    int r15 = lane & 15, quad = lane >> 4;
    int rb = blockIdx.x * 64;
    bool isf = DUALX && flags[1];

    stage_w(Wc + W_W1L, wbuf);          // stage early; barrier comes after agg
    if (DUALX) agg16_x(xself, isf, cnt, offN, csrb, tile, rb, wid, lane);
    else       agg16_bf16((const u16*)xself, cnt, offN, csrb, tile, rb, wid, lane);

    int ar = rb + wid * 16 + r15; if (ar > N_NODES - 1) ar = N_NODES - 1;
    bf16x8 ax[4];
#pragma unroll
    for (int ks = 0; ks < 4; ks++) {
        int ko = ks * 32 + quad * 8;
        ax[ks] = isf ? ldfrag_f32((const float*)xself, ar, ko)
                     : ldfrag((const u16*)xself, ar, ko);
    }
    __syncthreads();  // wbuf staged + (tile rows are wave-private; lgkmcnt handles)

    f32x4 acc[8] = {};
#pragma unroll
    for (int ks = 0; ks < 4; ks++) {
        int ko = ks * 32 + quad * 8;
        bf16x8 ag = ldfrag_lds(tile, wid * 16 + r15, ko);
#pragma unroll
        for (int ct = 0; ct < 8; ct++)
            acc[ct] = mfma16(ag, ldfrag_lds(wbuf, ct * 16 + r15, ko), acc[ct]);
    }
    __syncthreads();
    stage_w(Wc + W_W1R, wbuf);
    __syncthreads();
#pragma unroll
    for (int ks = 0; ks < 4; ks++) {
        int ko = ks * 32 + quad * 8;
#pragma unroll
        for (int ct = 0; ct < 8; ct++)
            acc[ct] = mfma16(ax[ks], ldfrag_lds(wbuf, ct * 16 + r15, ko), acc[ct]);
    }
#pragma unroll
    for (int ct = 0; ct < 8; ct++) {
        int col = ct * 16 + r15;
        float bb = b2f(Wc[W_B1 + col]);
#pragma unroll
        for (int r = 0; r < 4; r++) {
            int row = rb + wid * 16 + quad * 4 + r;
            if (row < N_NODES)
                h1[(size_t)row * 128 + col] = f2b(fmaxf(acc[ct][r] + bb, 0.f));
        }
    }
}

// ---- fused conv2+MLP: agg(h1)->tile; h2 = agg@W2l^T + h1@W2r^T + b2; decoder ----
__global__ __launch_bounds__(256) void k_fconv2(
    const u16* __restrict__ h1, const int* __restrict__ cnt,
    const int* __restrict__ offN, const u32* __restrict__ csrb,
    const u16* __restrict__ Wc, const int* __restrict__ flags,
    void* __restrict__ out) {
    __shared__ __align__(16) u16 wbuf[128 * TPITCH];  // 34.8 KB
    __shared__ __align__(16) u16 tile[64 * TPITCH];   // 17.4 KB -> 3 blocks/CU
    int wid = threadIdx.x >> 6, lane = threadIdx.x & 63;
    int r15 = lane & 15, quad = lane >> 4;
    int rb = blockIdx.x * 64;
    int arl = wid * 16 + r15;

    stage_w(Wc + W_W2L, wbuf);
    agg16_bf16(h1, cnt, offN, csrb, tile, rb, wid, lane);

    int ar = rb + arl; if (ar > N_NODES - 1) ar = N_NODES - 1;
    bf16x8 as[4], at[4];
#pragma unroll
    for (int ks = 0; ks < 4; ks++)
        as[ks] = ldfrag(h1, ar, ks * 32 + quad * 8);
    __syncthreads();  // wbuf staged

    f32x4 acc2[8] = {};
#pragma unroll
    for (int ks = 0; ks < 4; ks++) {
        int ko = ks * 32 + quad * 8;
        at[ks] = ldfrag_lds(tile, arl, ko);  // consume tile into regs (frees tile)
#pragma unroll
        for (int ct = 0; ct < 8; ct++)
            acc2[ct] = mfma16(at[ks], ldfrag_lds(wbuf, ct * 16 + r15, ko), acc2[ct]);
    }
    __syncthreads();
    stage_w(Wc + W_W2R, wbuf);
    __syncthreads();
#pragma unroll
    for (int ks = 0; ks < 4; ks++) {
        int ko = ks * 32 + quad * 8;
#pragma unroll
        for (int ct = 0; ct < 8; ct++)
            acc2[ct] = mfma16(as[ks], ldfrag_lds(wbuf, ct * 16 + r15, ko), acc2[ct]);
    }
#pragma unroll
    for (int ct = 0; ct < 8; ct++) {  // h2 -> tile (wave-private rows, already consumed)
        int col = ct * 16 + r15;
        float bb = b2f(Wc[W_B2 + col]);
#pragma unroll
        for (int r = 0; r < 4; r++) {
            int lr = wid * 16 + quad * 4 + r;
            tile[lr * TPITCH + col] = f2b(acc2[ct][r] + bb);
        }
    }
    __syncthreads();  // all W2r reads done before W3 restage

    float pr[4] = {};
    float b4f = b2f(Wc[W_B4]);
#pragma unroll
    for (int half = 0; half < 2; half++) {
        stage_w(Wc + W_W3 + half * 16384, wbuf);
        __syncthreads();
        f32x4 acc3[8] = {};
#pragma unroll
        for (int ks = 0; ks < 4; ks++) {
            int ko = ks * 32 + quad * 8;
            bf16x8 a = ldfrag_lds(tile, arl, ko);
#pragma unroll
            for (int ct = 0; ct < 8; ct++)
                acc3[ct] = mfma16(a, ldfrag_lds(wbuf, ct * 16 + r15, ko), acc3[ct]);
        }
#pragma unroll
        for (int ct = 0; ct < 8; ct++) {
            int col = half * 128 + ct * 16 + r15;
            float bb = b2f(Wc[W_B3 + col]);
            float w4 = b2f(Wc[W_W4 + col]);
#pragma unroll
            for (int r = 0; r < 4; r++)
                pr[r] += fmaxf(acc3[ct][r] + bb, 0.f) * w4;
        }
        __syncthreads();
    }
#pragma unroll
    for (int m = 1; m < 16; m <<= 1)
#pragma unroll
        for (int r = 0; r < 4; r++)
            pr[r] += __shfl_xor(pr[r], m, 64);
    if (r15 == 0) {
        int isf = flags[1];
#pragma unroll
        for (int r = 0; r < 4; r++) {
            int row = rb + wid * 16 + quad * 4 + r;
            if (row < N_NODES) {
                float v = pr[r] + b4f;
                if (isf) ((float*)out)[row] = v;
                else     ((u16*)out)[row] = f2b(v);
            }
        }
    }
}

// ============ SMALL-tier kernels (proven R5 path) ============
__global__ __launch_bounds__(256) void k_hist(const int* __restrict__ ei,
                                              int* __restrict__ cnt,
                                              const int* __restrict__ flags) {
    int e = blockIdx.x * 256 + threadIdx.x;
    if (e >= N_EDGES) return;
    int src, dst; load_edge(ei, flags[0], e, src, dst);
    if ((u32)src < N_NODES && (u32)dst < N_NODES) atomicAdd(&cnt[dst], 1);
}
__global__ __launch_bounds__(1024) void k_scan(int* __restrict__ cnt,
                                               int* __restrict__ off) {
    __shared__ int buf[1024];
    __shared__ int carry_s;
    int t = threadIdx.x;
    if (t == 0) carry_s = 0;
    __syncthreads();
    for (int base = 0; base < N_NODES; base += 1024) {
        int i = base + t;
        int v = (i < N_NODES) ? cnt[i] : 0;
        buf[t] = v;
        __syncthreads();
        for (int s = 1; s < 1024; s <<= 1) {
            int a = (t >= s) ? buf[t - s] : 0;
            __syncthreads();
            buf[t] += a;
            __syncthreads();
        }
        int carry = carry_s;
        if (i < N_NODES) {
            int excl = carry + buf[t] - v;
            off[i] = excl;
            cnt[i] = excl;
        }
        __syncthreads();
        if (t == 1023) carry_s = carry + buf[1023];
        __syncthreads();
    }
    if (t == 0) off[N_NODES] = carry_s;
}
__global__ __launch_bounds__(256) void k_csr(const int* __restrict__ ei,
                                             int* __restrict__ cursor,
                                             int* __restrict__ csr,
                                             const int* __restrict__ flags) {
    int e = blockIdx.x * 256 + threadIdx.x;
    if (e >= N_EDGES) return;
    int src, dst; load_edge(ei, flags[0], e, src, dst);
    if ((u32)src < N_NODES && (u32)dst < N_NODES) {
        int pos = atomicAdd(&cursor[dst], 1);
        if ((u32)pos < N_EDGES) csr[pos] = src;
    }
}
__device__ inline void agg_bf16(const u16* __restrict__ feat,
                                const int* __restrict__ off, const int* __restrict__ csr,
                                u16* tile, int rb, int wid, int lane) {
    const u32* f32p = (const u32*)feat;
    for (int rr = 0; rr < 32; rr++) {
        int lr = wid * 32 + rr;
        int node = rb + lr;
        float s0 = 0.f, s1 = 0.f;
        int deg = 0;
        if (node < N_NODES) {
            int s = off[node], e = off[node + 1];
            if (s < 0) s = 0;
            if (e > N_EDGES) e = N_EDGES;
            if (e < s) e = s;
            deg = e - s;
            for (int p = s; p < e; p++) {
                int nb = csr[p];
                if ((u32)nb >= N_NODES) nb = 0;
                u32 u = f32p[(size_t)nb * 64 + lane];
                s0 += b2f_lo(u); s1 += b2f_hi(u);
            }
        }
        float sc = deg > 0 ? 1.f / (float)deg : 0.f;
        u16 h0 = f2b(s0 * sc), h1 = f2b(s1 * sc);
        ((u32*)tile)[lr * (TPITCH / 2) + lane] = (u32)h0 | ((u32)h1 << 16);
    }
}
__device__ inline void agg_f32(const float* __restrict__ feat,
                               const int* __restrict__ off, const int* __restrict__ csr,
                               u16* tile, int rb, int wid, int lane) {
    const float2* fp = (const float2*)feat;
    for (int rr = 0; rr < 32; rr++) {
        int lr = wid * 32 + rr;
        int node = rb + lr;
        float s0 = 0.f, s1 = 0.f;
        int deg = 0;
        if (node < N_NODES) {
            int s = off[node], e = off[node + 1];
            if (s < 0) s = 0;
            if (e > N_EDGES) e = N_EDGES;
            if (e < s) e = s;
            deg = e - s;
            for (int p = s; p < e; p++) {
                int nb = csr[p];
                if ((u32)nb >= N_NODES) nb = 0;
                float2 v = fp[(size_t)nb * 64 + lane];
                s0 += v.x; s1 += v.y;
            }
        }
        float sc = deg > 0 ? 1.f / (float)deg : 0.f;
        u16 h0 = f2b(s0 * sc), h1 = f2b(s1 * sc);
        ((u32*)tile)[lr * (TPITCH / 2) + lane] = (u32)h0 | ((u32)h1 << 16);
    }
}
__global__ __launch_bounds__(256) void k_conv1(
    const void* __restrict__ x, const int* __restrict__ off, const int* __restrict__ csr,
    const u16* __restrict__ Wc, const int* __restrict__ flags,
    u16* __restrict__ h1) {
    __shared__ __align__(16) u16 tile[128 * TPITCH];
    int wid = threadIdx.x >> 6, lane = threadIdx.x & 63;
    int r15 = lane & 15, quad = lane >> 4;
    int rb = blockIdx.x * 128;
    int isf = flags[1];
    if (isf) agg_f32((const float*)x, off, csr, tile, rb, wid, lane);
    else     agg_bf16((const u16*)x, off, csr, tile, rb, wid, lane);
    __syncthreads();
    int ar0l = wid * 32 + r15, ar1l = ar0l + 16;
    int ar0g = rb + ar0l; if (ar0g > N_NODES - 1) ar0g = N_NODES - 1;
    int ar1g = rb + ar1l; if (ar1g > N_NODES - 1) ar1g = N_NODES - 1;
    bf16x8 ax0[4], ax1[4];
    if (isf) {
#pragma unroll
        for (int ks = 0; ks < 4; ks++) {
            int ko = ks * 32 + quad * 8;
            ax0[ks] = ldfrag_f32((const float*)x, ar0g, ko);
            ax1[ks] = ldfrag_f32((const float*)x, ar1g, ko);
        }
    } else {
#pragma unroll
        for (int ks = 0; ks < 4; ks++) {
            int ko = ks * 32 + quad * 8;
            ax0[ks] = ldfrag((const u16*)x, ar0g, ko);
            ax1[ks] = ldfrag((const u16*)x, ar1g, ko);
        }
    }
    f32x4 acc[2][8] = {};
#pragma unroll
    for (int ks = 0; ks < 4; ks++) {
        int ko = ks * 32 + quad * 8;
        bf16x8 a0t = ldfrag_lds(tile, ar0l, ko);
        bf16x8 a1t = ldfrag_lds(tile, ar1l, ko);
#pragma unroll
        for (int ct = 0; ct < 8; ct++) {
            bf16x8 bl = ldfrag(Wc + W_W1L, ct * 16 + r15, ko);
            bf16x8 br = ldfrag(Wc + W_W1R, ct * 16 + r15, ko);
            acc[0][ct] = mfma16(a0t, bl, acc[0][ct]);
            acc[0][ct] = mfma16(ax0[ks], br, acc[0][ct]);
            acc[1][ct] = mfma16(a1t, bl, acc[1][ct]);
            acc[1][ct] = mfma16(ax1[ks], br, acc[1][ct]);
        }
    }
#pragma unroll
    for (int ct = 0; ct < 8; ct++) {
        int col = ct * 16 + r15;
        float bb = b2f(Wc[W_B1 + col]);
#pragma unroll
        for (int rt = 0; rt < 2; rt++) {
#pragma unroll
            for (int r = 0; r < 4; r++) {
                int row = rb + wid * 32 + rt * 16 + quad * 4 + r;
                if (row < N_NODES)
                    h1[(size_t)row * 128 + col] = f2b(fmaxf(acc[rt][ct][r] + bb, 0.f));
            }
        }
    }
}
__global__ __launch_bounds__(256) void k_conv2mlp(
    const u16* __restrict__ h1, const int* __restrict__ off, const int* __restrict__ csr,
    const u16* __restrict__ Wc, const int* __restrict__ flags,
    void* __restrict__ out) {
    __shared__ __align__(16) u16 tile[128 * TPITCH];
    int wid = threadIdx.x >> 6, lane = threadIdx.x & 63;
    int r15 = lane & 15, quad = lane >> 4;
    int rb = blockIdx.x * 128;
    agg_bf16(h1, off, csr, tile, rb, wid, lane);
    __syncthreads();
    int ar0l = wid * 32 + r15, ar1l = ar0l + 16;
    int ar0g = rb + ar0l; if (ar0g > N_NODES - 1) ar0g = N_NODES - 1;
    int ar1g = rb + ar1l; if (ar1g > N_NODES - 1) ar1g = N_NODES - 1;
    f32x4 acc2[2][8] = {};
#pragma unroll
    for (int ks = 0; ks < 4; ks++) {
        int ko = ks * 32 + quad * 8;
        bf16x8 a0t = ldfrag_lds(tile, ar0l, ko);
        bf16x8 a1t = ldfrag_lds(tile, ar1l, ko);
        bf16x8 a0s = ldfrag(h1, ar0g, ko);
        bf16x8 a1s = ldfrag(h1, ar1g, ko);
#pragma unroll
        for (int ct = 0; ct < 8; ct++) {
            bf16x8 bl = ldfrag(Wc + W_W2L, ct * 16 + r15, ko);
            bf16x8 br = ldfrag(Wc + W_W2R, ct * 16 + r15, ko);
            acc2[0][ct] = mfma16(a0t, bl, acc2[0][ct]);
            acc2[0][ct] = mfma16(a0s, br, acc2[0][ct]);
            acc2[1][ct] = mfma16(a1t, bl, acc2[1][ct]);
            acc2[1][ct] = mfma16(a1s, br, acc2[1][ct]);
        }
    }
    __syncthreads();
#pragma unroll
    for (int ct = 0; ct < 8; ct++) {
        int col = ct * 16 + r15;
        float bb = b2f(Wc[W_B2 + col]);
#pragma unroll
        for (int rt = 0; rt < 2; rt++) {
#pragma unroll
            for (int r = 0; r < 4; r++) {
                int lr = wid * 32 + rt * 16 + quad * 4 + r;
                tile[lr * TPITCH + col] = f2b(acc2[rt][ct][r] + bb);
            }
        }
    }
    __syncthreads();
    float pr[2][4] = {};
    float b4f = b2f(Wc[W_B4]);
#pragma unroll
    for (int half = 0; half < 2; half++) {
        f32x4 acc3[2][8] = {};
#pragma unroll
        for (int ks = 0; ks < 4; ks++) {
            int ko = ks * 32 + quad * 8;
            bf16x8 a0 = ldfrag_lds(tile, ar0l, ko);
            bf16x8 a1 = ldfrag_lds(tile, ar1l, ko);
#pragma unroll
            for (int ct = 0; ct < 8; ct++) {
                bf16x8 b = ldfrag(Wc + W_W3, half * 128 + ct * 16 + r15, ko);
                acc3[0][ct] = mfma16(a0, b, acc3[0][ct]);
                acc3[1][ct] = mfma16(a1, b, acc3[1][ct]);
            }
        }
#pragma unroll
        for (int ct = 0; ct < 8; ct++) {
            int col = half * 128 + ct * 16 + r15;
            float bb = b2f(Wc[W_B3 + col]);
            float w4 = b2f(Wc[W_W4 + col]);
#pragma unroll
            for (int rt = 0; rt < 2; rt++)
#pragma unroll
                for (int r = 0; r < 4; r++)
                    pr[rt][r] += fmaxf(acc3[rt][ct][r] + bb, 0.f) * w4;
        }
    }
#pragma unroll
    for (int m = 1; m < 16; m <<= 1)
#pragma unroll
        for (int rt = 0; rt < 2; rt++)
#pragma unroll
            for (int r = 0; r < 4; r++)
                pr[rt][r] += __shfl_xor(pr[rt][r], m, 64);
    if (r15 == 0) {
        int isf = flags[1];
#pragma unroll
        for (int rt = 0; rt < 2; rt++) {
#pragma unroll
            for (int r = 0; r < 4; r++) {
                int row = rb + wid * 32 + rt * 16 + quad * 4 + r;
                if (row < N_NODES) {
                    float v = pr[rt][r] + b4f;
                    if (isf) ((float*)out)[row] = v;
                    else     ((u16*)out)[row] = f2b(v);
                }
            }
        }
    }
}

extern "C" void kernel_launch(void* const* d_in, const int* in_sizes, int n_in,
                              void* d_out, int out_size, void* d_ws, size_t ws_size,
                              hipStream_t stream) {
    const void* x  = d_in[0];
    const int* ei  = (const int*)d_in[1];

    const size_t A = 256;
    const size_t sFlg  = 256;
    const size_t sGcur = 1024;
    const size_t sGh   = (((size_t)NBIN * NPART * 4) + A - 1) & ~(A - 1);
    const size_t sCnt  = (((size_t)N_NODES * 4) + A - 1) & ~(A - 1);
    const size_t sOffN = (((size_t)N_NODES * 4) + A - 1) & ~(A - 1);
    const size_t sWc   = ((WTOT * 2) + A - 1) & ~(A - 1);
    const size_t sCsrB = (((size_t)NBIN * BCAP * 4) + A - 1) & ~(A - 1);   // 9.63 MB
    const size_t sFB   = (((size_t)N_NODES * 128 * 2) + A - 1) & ~(A - 1); // 25.6 MB
    const size_t sOff  = (((size_t)(N_NODES + 1) * 4) + A - 1) & ~(A - 1);
    const size_t sCsr  = (((size_t)N_EDGES * 4) + A - 1) & ~(A - 1);
    // fused tier: flags|gcur|ghist|gbase|cnt|offN|Wc|csrB|h1(gbuf alias)|[xb]
    const size_t needF1 = sFlg + sGcur + 2 * sGh + sCnt + sOffN + sWc + sCsrB + sFB;  // ~37.1MB
    const size_t needF0 = needF1 + sFB;                                                // ~62.7MB
    const size_t needS  = sFlg + sCnt + sOff + sCsr + sFB;                             // ~32.8MB

    char* ws = (char*)d_ws;
    int gconv = (N_NODES + 63) / 64;   // 1563 blocks

    CvtArgs ca;
    const int srcIdx[10] = {2, 4, 5, 7, 8, 10, 3, 6, 9, 11};
    const int offs[10] = {W_W1L, W_W1R, W_W2L, W_W2R, W_W3, W_W4, W_B1, W_B2, W_B3, W_B4};
    const int ns[10]   = {16384, 16384, 16384, 16384, 32768, 256, 128, 128, 256, 1};
    for (int i = 0; i < 10; i++) { ca.src[i] = d_in[srcIdx[i]]; ca.off[i] = offs[i]; ca.n[i] = ns[i]; }

    if (ws_size >= needF1) {
        bool t0 = ws_size >= needF0;
        int* flags = (int*)ws;
        int* gcur  = (int*)(ws + sFlg);
        int* ghist = (int*)(ws + sFlg + sGcur);
        int* gbase = (int*)(ws + sFlg + sGcur + sGh);
        int* cnt   = (int*)(ws + sFlg + sGcur + 2 * sGh);
        int* offN  = (int*)(ws + sFlg + sGcur + 2 * sGh + sCnt);
        u16* Wc    = (u16*)(ws + sFlg + sGcur + 2 * sGh + sCnt + sOffN);
        u32* csrb  = (u32*)(ws + sFlg + sGcur + 2 * sGh + sCnt + sOffN + sWc);
        u16* h1    = (u16*)(ws + sFlg + sGcur + 2 * sGh + sCnt + sOffN + sWc + sCsrB);
        u32* gbuf  = (u32*)h1;        // dead after k_binB; h1 written later by fconv1
        u16* xb    = h1 + (sFB / 2);  // T0 only

        hipMemsetAsync(ws, 0, sFlg, stream);
        k_detects<<<2, 256, 0, stream>>>((const u64*)ei, (const u32*)x, flags);
        k_rhist<<<NPART, 256, 0, stream>>>(ei, ghist, flags);
        k_rscan<<<NBIN, 512, 0, stream>>>(ghist, gbase, gcur);
        k_rscatter<<<NPART, 256, 0, stream>>>(ei, gbase, gbuf, flags);
        k_binB<<<NBIN, 512, 0, stream>>>(gcur, gbuf, csrb, cnt, offN);
        k_cvtw<<<(WTOT + 255) / 256, 256, 0, stream>>>(ca, Wc, flags);

        if (t0) {
            k_cvtx<<<((N_NODES * 128 / 4) + 255) / 256, 256, 0, stream>>>(x, xb, flags);
            k_fconv1<false><<<gconv, 256, 0, stream>>>(xb, cnt, offN, csrb, Wc, flags, h1);
        } else {
            k_fconv1<true><<<gconv, 256, 0, stream>>>(x, cnt, offN, csrb, Wc, flags, h1);
        }
        k_fconv2<<<gconv, 256, 0, stream>>>(h1, cnt, offN, csrb, Wc, flags, d_out);
    } else if (ws_size >= needS) {
        int* flags = (int*)ws;
        int* cnt   = (int*)(ws + sFlg);
        u16* Wc    = (u16*)(ws + sFlg);
        int* off   = (int*)(ws + sFlg + sCnt);
        int* csr   = (int*)(ws + sFlg + sCnt + sOff);
        u16* h1    = (u16*)(ws + sFlg + sCnt + sOff + sCsr);

        hipMemsetAsync(ws, 0, sFlg + (size_t)N_NODES * 4, stream);
        k_detects<<<2, 256, 0, stream>>>((const u64*)ei, (const u32*)x, flags);
        k_hist<<<N_EDGES / 256, 256, 0, stream>>>(ei, cnt, flags);
        k_scan<<<1, 1024, 0, stream>>>(cnt, off);
        k_csr<<<N_EDGES / 256, 256, 0, stream>>>(ei, cnt, csr, flags);
        k_cvtw<<<(WTOT + 255) / 256, 256, 0, stream>>>(ca, Wc, flags);
        k_conv1<<<(N_NODES + 127) / 128, 256, 0, stream>>>(x, off, csr, Wc, flags, h1);
        k_conv2mlp<<<(N_NODES + 127) / 128, 256, 0, stream>>>(h1, off, csr, Wc, flags, d_out);
    } else {
        k_diag<<<(N_NODES + 255) / 256, 256, 0, stream>>>(
            (u16*)d_out, 2000.0f + (float)(ws_size >> 20));
    }
}

// Round 13
// 331.595 us; speedup vs baseline: 1.5569x; 1.5569x over previous
//
#include <hip/hip_runtime.h>

typedef unsigned short u16;
typedef unsigned int u32;
typedef unsigned long long u64;

#define N_NODES 100000
#define N_EDGES 1600000
#define TPITCH 136   // LDS pitch (u16): 272B rows, 16B-aligned
#define NBIN 196     // ceil(N_NODES/512)
#define BCAP 12288   // per-bin pair capacity
#define NPART 512    // radix partition blocks
#define EPB 3125     // edges per partition

typedef __bf16 bf16x8 __attribute__((ext_vector_type(8)));
typedef float  f32x4  __attribute__((ext_vector_type(4)));

__device__ inline float b2f(u16 b) { return __uint_as_float(((u32)b) << 16); }
__device__ inline float b2f_lo(u32 u) { return __uint_as_float(u << 16); }
__device__ inline float b2f_hi(u32 u) { return __uint_as_float(u & 0xffff0000u); }
__device__ inline u16 f2b(float f) {  // RNE float->bf16
    u32 u = __float_as_uint(f);
    return (u16)((u + 0x7fffu + ((u >> 16) & 1u)) >> 16);
}

__device__ inline bf16x8 ldfrag(const u16* base, int row, int k) {
    union { uint4 u; bf16x8 v; } t;
    t.u = *(const uint4*)(base + (size_t)row * 128 + k);
    return t.v;
}
__device__ inline bf16x8 ldfrag_f32(const float* base, int row, int k) {
    const float4* p = (const float4*)(base + (size_t)row * 128 + k);
    float4 a = p[0], b = p[1];
    union { u16 h[8]; bf16x8 v; } t;
    t.h[0] = f2b(a.x); t.h[1] = f2b(a.y); t.h[2] = f2b(a.z); t.h[3] = f2b(a.w);
    t.h[4] = f2b(b.x); t.h[5] = f2b(b.y); t.h[6] = f2b(b.z); t.h[7] = f2b(b.w);
    return t.v;
}
__device__ inline bf16x8 ldfrag_lds(const u16* tile, int lrow, int k) {
    union { uint4 u; bf16x8 v; } t;
    t.u = *(const uint4*)(tile + lrow * TPITCH + k);
    return t.v;
}
__device__ inline f32x4 mfma16(bf16x8 a, bf16x8 b, f32x4 c) {
    return __builtin_amdgcn_mfma_f32_16x16x32_bf16(a, b, c, 0, 0, 0);
}

// cooperative stage: 128x128 bf16 = 2048 16B chunks; 256 thr x 8 iters
__device__ inline void stage_w(const u16* __restrict__ g, u16* lds) {
    int t = threadIdx.x;
#pragma unroll
    for (int i = 0; i < 8; i++) {
        int u = t + i * 256;
        int row = u >> 4, k = (u & 15) * 8;
        *(uint4*)(lds + row * TPITCH + k) = *(const uint4*)(g + row * 128 + k);
    }
}

// ---- diagnostic ----
__global__ __launch_bounds__(256) void k_diag(u16* __restrict__ out, float val) {
    int i = blockIdx.x * 256 + threadIdx.x;
    if (i < N_NODES) out[i] = f2b(val);
}

// ---- combined detect ----
__global__ __launch_bounds__(256) void k_detects(const u64* __restrict__ e,
                                                 const u32* __restrict__ x,
                                                 int* __restrict__ flags) {
    int t = threadIdx.x;
    if (blockIdx.x == 0) {
        u64 v = 0;
#pragma unroll
        for (int i = 0; i < 4; i++) v |= e[t + 256 * i];
        if (v >> 32) atomicOr(&flags[0], 1);
    } else {
        int bad = 0;
#pragma unroll
        for (int i = 0; i < 4; i++) {
            u32 w = x[t + 256 * i];
            u32 ex = (w >> 7) & 0xff;
            if (ex < 100 || ex > 140) bad = 1;
        }
        if (bad) atomicOr(&flags[1], 1);
    }
}

__device__ inline void load_edge(const int* ei, int is32, int e, int& src, int& dst) {
    if (is32) {
        src = ei[e]; dst = ei[N_EDGES + e];
    } else {
        const long long* e64 = (const long long*)ei;
        src = (int)e64[e]; dst = (int)e64[N_EDGES + e];
    }
}

// ---- radix partition build (proven R9/R11) ----
__global__ __launch_bounds__(256) void k_rhist(const int* __restrict__ ei,
                                               int* __restrict__ ghist,
                                               const int* __restrict__ flags) {
    __shared__ int hist[NBIN];
    int p = blockIdx.x, t = threadIdx.x;
    for (int i = t; i < NBIN; i += 256) hist[i] = 0;
    __syncthreads();
    int is32 = flags[0];
    int base = p * EPB;
    int end = base + EPB; if (end > N_EDGES) end = N_EDGES;
    for (int e = base + t; e < end; e += 256) {
        int src, dst; load_edge(ei, is32, e, src, dst);
        if ((u32)src < N_NODES && (u32)dst < N_NODES) atomicAdd(&hist[dst >> 9], 1);
    }
    __syncthreads();
    for (int i = t; i < NBIN; i += 256) ghist[i * NPART + p] = hist[i];
}
__global__ __launch_bounds__(512) void k_rscan(const int* __restrict__ ghist,
                                               int* __restrict__ gbase,
                                               int* __restrict__ gcur) {
    __shared__ int buf[NPART];
    int b = blockIdx.x, t = threadIdx.x;
    int v = ghist[b * NPART + t];
    buf[t] = v;
    __syncthreads();
    for (int s = 1; s < NPART; s <<= 1) {
        int a = (t >= s) ? buf[t - s] : 0;
        __syncthreads();
        buf[t] += a;
        __syncthreads();
    }
    gbase[b * NPART + t] = buf[t] - v;
    if (t == NPART - 1) gcur[b] = buf[t];
}
__global__ __launch_bounds__(256) void k_rscatter(const int* __restrict__ ei,
                                                  const int* __restrict__ gbase,
                                                  u32* __restrict__ gbuf,
                                                  const int* __restrict__ flags) {
    __shared__ int cur[NBIN];
    int p = blockIdx.x, t = threadIdx.x;
    for (int i = t; i < NBIN; i += 256) cur[i] = gbase[i * NPART + p];
    __syncthreads();
    int is32 = flags[0];
    int base = p * EPB;
    int end = base + EPB; if (end > N_EDGES) end = N_EDGES;
    for (int e = base + t; e < end; e += 256) {
        int src, dst; load_edge(ei, is32, e, src, dst);
        if ((u32)src < N_NODES && (u32)dst < N_NODES) {
            int bin = dst >> 9;
            int pos = atomicAdd(&cur[bin], 1);
            if (pos < BCAP)
                gbuf[(size_t)bin * BCAP + pos] = ((u32)(dst & 511) << 17) | (u32)src;
        }
    }
}
__global__ __launch_bounds__(512) void k_binB(const int* __restrict__ gcur,
                                              const u32* __restrict__ gbuf,
                                              u32* __restrict__ csr,
                                              int* __restrict__ cnt,
                                              int* __restrict__ offN) {
    __shared__ int hist[512];
    __shared__ int pfx[512];
    __shared__ int cur[512];
    __shared__ u32 srcbuf[BCAP];
    int b = blockIdx.x, t = threadIdx.x;
    int n = gcur[b]; if (n > BCAP) n = BCAP;
    hist[t] = 0;
    __syncthreads();
    for (int i = t; i < n; i += 512)
        atomicAdd(&hist[gbuf[(size_t)b * BCAP + i] >> 17], 1);
    __syncthreads();
    pfx[t] = hist[t];
    __syncthreads();
    for (int s = 1; s < 512; s <<= 1) {
        int a = (t >= s) ? pfx[t - s] : 0;
        __syncthreads();
        pfx[t] += a;
        __syncthreads();
    }
    int excl = pfx[t] - hist[t];
    cur[t] = excl;
    __syncthreads();
    for (int i = t; i < n; i += 512) {
        u32 p = gbuf[(size_t)b * BCAP + i];
        int pos = atomicAdd(&cur[p >> 17], 1);
        if (pos < BCAP) srcbuf[pos] = p & 0x1FFFFu;
    }
    __syncthreads();
    int total = pfx[511];
    for (int i = t; i < total; i += 512)
        csr[(size_t)b * BCAP + i] = srcbuf[i];
    int node = b * 512 + t;
    if (node < N_NODES) {
        cnt[node] = hist[t];
        offN[node] = b * BCAP + excl;
    }
}

// ---- weight normalization -> bf16 ----
#define WTOT 99073
struct CvtArgs { const void* src[10]; int off[10]; int n[10]; };
__global__ __launch_bounds__(256) void k_cvtw(CvtArgs a, u16* __restrict__ dst,
                                              const int* __restrict__ flags) {
    int i = blockIdx.x * 256 + threadIdx.x;
    if (i >= WTOT) return;
    int isf = flags[1];
    int s = 0;
    while (s < 9 && i >= a.off[s + 1]) s++;
    int j = i - a.off[s];
    float v = isf ? ((const float*)a.src[s])[j] : b2f(((const u16*)a.src[s])[j]);
    dst[i] = f2b(v);
}
#define W_W1L 0
#define W_W1R 16384
#define W_W2L 32768
#define W_W2R 49152
#define W_W3  65536
#define W_W4  98304
#define W_B1  98560
#define W_B2  98688
#define W_B3  98816
#define W_B4  99072

// ---- x -> bf16 convert ----
__global__ __launch_bounds__(256) void k_cvtx(const void* __restrict__ x,
                                              u16* __restrict__ xb,
                                              const int* __restrict__ flags) {
    int i = blockIdx.x * 256 + threadIdx.x;
    if ((size_t)i * 4 >= (size_t)N_NODES * 128) return;
    if (flags[1]) {
        float4 v = ((const float4*)x)[i];
        union { u16 h[4]; u64 q; } t;
        t.h[0] = f2b(v.x); t.h[1] = f2b(v.y); t.h[2] = f2b(v.z); t.h[3] = f2b(v.w);
        ((u64*)xb)[i] = t.q;
    } else {
        ((u64*)xb)[i] = ((const u64*)x)[i];
    }
}

// ---- compact-CSR agg, bf16 features: one wave/node, 8-deep ILP ----
__global__ __launch_bounds__(256) void k_aggc(const u16* __restrict__ feat,
                                              const int* __restrict__ cnt,
                                              const int* __restrict__ offN,
                                              const u32* __restrict__ csr,
                                              u16* __restrict__ outb) {
    int node = blockIdx.x * 4 + (threadIdx.x >> 6);
    if (node >= N_NODES) return;
    int lane = threadIdx.x & 63;
    int deg = cnt[node];
    int s = offN[node];
    const u32* f = (const u32*)feat;
    float a0 = 0, a1 = 0, b0 = 0, b1 = 0, c0 = 0, c1 = 0, d0 = 0, d1 = 0;
    float e0 = 0, e1 = 0, g0 = 0, g1 = 0, h0f = 0, h1f = 0, i0 = 0, i1 = 0;
    int p = 0;
    for (; p + 7 < deg; p += 8) {
        u32 n0 = csr[s + p],     n1 = csr[s + p + 1], n2 = csr[s + p + 2], n3 = csr[s + p + 3];
        u32 n4 = csr[s + p + 4], n5 = csr[s + p + 5], n6 = csr[s + p + 6], n7 = csr[s + p + 7];
        if (n0 >= N_NODES) n0 = 0;
        if (n1 >= N_NODES) n1 = 0;
        if (n2 >= N_NODES) n2 = 0;
        if (n3 >= N_NODES) n3 = 0;
        if (n4 >= N_NODES) n4 = 0;
        if (n5 >= N_NODES) n5 = 0;
        if (n6 >= N_NODES) n6 = 0;
        if (n7 >= N_NODES) n7 = 0;
        u32 w0 = f[(size_t)n0 * 64 + lane];
        u32 w1 = f[(size_t)n1 * 64 + lane];
        u32 w2 = f[(size_t)n2 * 64 + lane];
        u32 w3 = f[(size_t)n3 * 64 + lane];
        u32 w4 = f[(size_t)n4 * 64 + lane];
        u32 w5 = f[(size_t)n5 * 64 + lane];
        u32 w6 = f[(size_t)n6 * 64 + lane];
        u32 w7 = f[(size_t)n7 * 64 + lane];
        a0 += b2f_lo(w0); a1 += b2f_hi(w0);
        b0 += b2f_lo(w1); b1 += b2f_hi(w1);
        c0 += b2f_lo(w2); c1 += b2f_hi(w2);
        d0 += b2f_lo(w3); d1 += b2f_hi(w3);
        e0 += b2f_lo(w4); e1 += b2f_hi(w4);
        g0 += b2f_lo(w5); g1 += b2f_hi(w5);
        h0f += b2f_lo(w6); h1f += b2f_hi(w6);
        i0 += b2f_lo(w7); i1 += b2f_hi(w7);
    }
    for (; p + 3 < deg; p += 4) {
        u32 n0 = csr[s + p], n1 = csr[s + p + 1], n2 = csr[s + p + 2], n3 = csr[s + p + 3];
        if (n0 >= N_NODES) n0 = 0;
        if (n1 >= N_NODES) n1 = 0;
        if (n2 >= N_NODES) n2 = 0;
        if (n3 >= N_NODES) n3 = 0;
        u32 w0 = f[(size_t)n0 * 64 + lane];
        u32 w1 = f[(size_t)n1 * 64 + lane];
        u32 w2 = f[(size_t)n2 * 64 + lane];
        u32 w3 = f[(size_t)n3 * 64 + lane];
        a0 += b2f_lo(w0); a1 += b2f_hi(w0);
        b0 += b2f_lo(w1); b1 += b2f_hi(w1);
        c0 += b2f_lo(w2); c1 += b2f_hi(w2);
        d0 += b2f_lo(w3); d1 += b2f_hi(w3);
    }
    for (; p < deg; p++) {
        u32 n0 = csr[s + p];
        if (n0 >= N_NODES) n0 = 0;
        u32 w0 = f[(size_t)n0 * 64 + lane];
        a0 += b2f_lo(w0); a1 += b2f_hi(w0);
    }
    float s0 = ((a0 + b0) + (c0 + d0)) + ((e0 + g0) + (h0f + i0));
    float s1 = ((a1 + b1) + (c1 + d1)) + ((e1 + g1) + (h1f + i1));
    float sc = deg > 0 ? 1.f / (float)deg : 0.f;
    u16 o0 = f2b(s0 * sc), o1 = f2b(s1 * sc);
    ((u32*)outb)[(size_t)node * 64 + lane] = (u32)o0 | ((u32)o1 << 16);
}

// ---- compact-CSR agg, dual-dtype raw x (T1) ----
__global__ __launch_bounds__(256) void k_aggcx(const void* __restrict__ x,
                                               const int* __restrict__ cnt,
                                               const int* __restrict__ offN,
                                               const u32* __restrict__ csr,
                                               const int* __restrict__ flags,
                                               u16* __restrict__ outb) {
    int node = blockIdx.x * 4 + (threadIdx.x >> 6);
    if (node >= N_NODES) return;
    int lane = threadIdx.x & 63;
    int deg = cnt[node];
    int s = offN[node];
    float a0 = 0, a1 = 0, b0 = 0, b1 = 0;
    int p = 0;
    if (flags[1]) {
        const float2* f = (const float2*)x;
        for (; p + 1 < deg; p += 2) {
            u32 n0 = csr[s + p], n1 = csr[s + p + 1];
            if (n0 >= N_NODES) n0 = 0;
            if (n1 >= N_NODES) n1 = 0;
            float2 w0 = f[(size_t)n0 * 64 + lane];
            float2 w1 = f[(size_t)n1 * 64 + lane];
            a0 += w0.x; a1 += w0.y; b0 += w1.x; b1 += w1.y;
        }
        for (; p < deg; p++) {
            u32 n0 = csr[s + p];
            if (n0 >= N_NODES) n0 = 0;
            float2 w0 = f[(size_t)n0 * 64 + lane];
            a0 += w0.x; a1 += w0.y;
        }
    } else {
        const u32* f = (const u32*)x;
        for (; p + 1 < deg; p += 2) {
            u32 n0 = csr[s + p], n1 = csr[s + p + 1];
            if (n0 >= N_NODES) n0 = 0;
            if (n1 >= N_NODES) n1 = 0;
            u32 w0 = f[(size_t)n0 * 64 + lane];
            u32 w1 = f[(size_t)n1 * 64 + lane];
            a0 += b2f_lo(w0); a1 += b2f_hi(w0);
            b0 += b2f_lo(w1); b1 += b2f_hi(w1);
        }
        for (; p < deg; p++) {
            u32 n0 = csr[s + p];
            if (n0 >= N_NODES) n0 = 0;
            u32 w0 = f[(size_t)n0 * 64 + lane];
            a0 += b2f_lo(w0); a1 += b2f_hi(w0);
        }
    }
    float s0 = a0 + b0, s1 = a1 + b1;
    float sc = deg > 0 ? 1.f / (float)deg : 0.f;
    u16 o0 = f2b(s0 * sc), o1 = f2b(s1 * sc);
    ((u32*)outb)[(size_t)node * 64 + lane] = (u32)o0 | ((u32)o1 << 16);
}

// ---- conv1, 64 rows/block, W1l/W1r LDS-staged sequentially ----
template <bool DUALX>
__global__ __launch_bounds__(256) void k_conv1f(
    const u16* __restrict__ aggA, const void* __restrict__ xself,
    const u16* __restrict__ Wc, const int* __restrict__ flags,
    u16* __restrict__ h1) {
    __shared__ __align__(16) u16 wbuf[128 * TPITCH];  // 34.8 KB -> 4 blocks/CU
    int wid = threadIdx.x >> 6, lane = threadIdx.x & 63;
    int r15 = lane & 15, quad = lane >> 4;
    int rb = blockIdx.x * 64;
    int ar = rb + wid * 16 + r15; if (ar > N_NODES - 1) ar = N_NODES - 1;

    bf16x8 ag[4], ax[4];
    bool isf = DUALX && flags[1];
#pragma unroll
    for (int ks = 0; ks < 4; ks++) {
        int ko = ks * 32 + quad * 8;
        ag[ks] = ldfrag(aggA, ar, ko);
        ax[ks] = isf ? ldfrag_f32((const float*)xself, ar, ko)
                     : ldfrag((const u16*)xself, ar, ko);
    }
    f32x4 acc[8] = {};
    stage_w(Wc + W_W1L, wbuf);
    __syncthreads();
#pragma unroll
    for (int ks = 0; ks < 4; ks++) {
        int ko = ks * 32 + quad * 8;
#pragma unroll
        for (int ct = 0; ct < 8; ct++)
            acc[ct] = mfma16(ag[ks], ldfrag_lds(wbuf, ct * 16 + r15, ko), acc[ct]);
    }
    __syncthreads();
    stage_w(Wc + W_W1R, wbuf);
    __syncthreads();
#pragma unroll
    for (int ks = 0; ks < 4; ks++) {
        int ko = ks * 32 + quad * 8;
#pragma unroll
        for (int ct = 0; ct < 8; ct++)
            acc[ct] = mfma16(ax[ks], ldfrag_lds(wbuf, ct * 16 + r15, ko), acc[ct]);
    }
#pragma unroll
    for (int ct = 0; ct < 8; ct++) {
        int col = ct * 16 + r15;
        float bb = b2f(Wc[W_B1 + col]);
#pragma unroll
        for (int r = 0; r < 4; r++) {
            int row = rb + wid * 16 + quad * 4 + r;
            if (row < N_NODES)
                h1[(size_t)row * 128 + col] = f2b(fmaxf(acc[ct][r] + bb, 0.f));
        }
    }
}

// ---- conv2+MLP, 64 rows/block, all weights LDS-staged ----
__global__ __launch_bounds__(256) void k_conv2f(
    const u16* __restrict__ aggH, const u16* __restrict__ h1,
    const u16* __restrict__ Wc, const int* __restrict__ flags,
    void* __restrict__ out) {
    __shared__ __align__(16) u16 wbuf[128 * TPITCH];  // 34.8 KB
    __shared__ __align__(16) u16 tile[64 * TPITCH];   // 17.4 KB -> 3 blocks/CU
    int wid = threadIdx.x >> 6, lane = threadIdx.x & 63;
    int r15 = lane & 15, quad = lane >> 4;
    int rb = blockIdx.x * 64;
    int ar = rb + wid * 16 + r15; if (ar > N_NODES - 1) ar = N_NODES - 1;
    int arl = wid * 16 + r15;

    bf16x8 at[4], as[4];
#pragma unroll
    for (int ks = 0; ks < 4; ks++) {
        int ko = ks * 32 + quad * 8;
        at[ks] = ldfrag(aggH, ar, ko);
        as[ks] = ldfrag(h1, ar, ko);
    }
    f32x4 acc2[8] = {};
    stage_w(Wc + W_W2L, wbuf);
    __syncthreads();
#pragma unroll
    for (int ks = 0; ks < 4; ks++) {
        int ko = ks * 32 + quad * 8;
#pragma unroll
        for (int ct = 0; ct < 8; ct++)
            acc2[ct] = mfma16(at[ks], ldfrag_lds(wbuf, ct * 16 + r15, ko), acc2[ct]);
    }
    __syncthreads();
    stage_w(Wc + W_W2R, wbuf);
    __syncthreads();
#pragma unroll
    for (int ks = 0; ks < 4; ks++) {
        int ko = ks * 32 + quad * 8;
#pragma unroll
        for (int ct = 0; ct < 8; ct++)
            acc2[ct] = mfma16(as[ks], ldfrag_lds(wbuf, ct * 16 + r15, ko), acc2[ct]);
    }
#pragma unroll
    for (int ct = 0; ct < 8; ct++) {  // h2 -> tile (wave-local rows; wbuf untouched)
        int col = ct * 16 + r15;
        float bb = b2f(Wc[W_B2 + col]);
#pragma unroll
        for (int r = 0; r < 4; r++) {
            int lr = wid * 16 + quad * 4 + r;
            tile[lr * TPITCH + col] = f2b(acc2[ct][r] + bb);
        }
    }
    __syncthreads();  // W2r reads done + h2 visible

    float pr[4] = {};
    float b4f = b2f(Wc[W_B4]);
#pragma unroll
    for (int half = 0; half < 2; half++) {
        stage_w(Wc + W_W3 + half * 16384, wbuf);
        __syncthreads();
        f32x4 acc3[8] = {};
#pragma unroll
        for (int ks = 0; ks < 4; ks++) {
            int ko = ks * 32 + quad * 8;
            bf16x8 a = ldfrag_lds(tile, arl, ko);
#pragma unroll
            for (int ct = 0; ct < 8; ct++)
                acc3[ct] = mfma16(a, ldfrag_lds(wbuf, ct * 16 + r15, ko), acc3[ct]);
        }
#pragma unroll
        for (int ct = 0; ct < 8; ct++) {
            int col = half * 128 + ct * 16 + r15;
            float bb = b2f(Wc[W_B3 + col]);
            float w4 = b2f(Wc[W_W4 + col]);
#pragma unroll
            for (int r = 0; r < 4; r++)
                pr[r] += fmaxf(acc3[ct][r] + bb, 0.f) * w4;
        }
        __syncthreads();  // done reading this W3 half before restage
    }
#pragma unroll
    for (int m = 1; m < 16; m <<= 1)
#pragma unroll
        for (int r = 0; r < 4; r++)
            pr[r] += __shfl_xor(pr[r], m, 64);
    if (r15 == 0) {
        int isf = flags[1];
#pragma unroll
        for (int r = 0; r < 4; r++) {
            int row = rb + wid * 16 + quad * 4 + r;
            if (row < N_NODES) {
                float v = pr[r] + b4f;
                if (isf) ((float*)out)[row] = v;
                else     ((u16*)out)[row] = f2b(v);
            }
        }
    }
}

// ============ SMALL-tier kernels (proven R5 path) ============
__global__ __launch_bounds__(256) void k_hist(const int* __restrict__ ei,
                                              int* __restrict__ cnt,
                                              const int* __restrict__ flags) {
    int e = blockIdx.x * 256 + threadIdx.x;
    if (e >= N_EDGES) return;
    int src, dst; load_edge(ei, flags[0], e, src, dst);
    if ((u32)src < N_NODES && (u32)dst < N_NODES) atomicAdd(&cnt[dst], 1);
}
__global__ __launch_bounds__(1024) void k_scan(int* __restrict__ cnt,
                                               int* __restrict__ off) {
    __shared__ int buf[1024];
    __shared__ int carry_s;
    int t = threadIdx.x;
    if (t == 0) carry_s = 0;
    __syncthreads();
    for (int base = 0; base < N_NODES; base += 1024) {
        int i = base + t;
        int v = (i < N_NODES) ? cnt[i] : 0;
        buf[t] = v;
        __syncthreads();
        for (int s = 1; s < 1024; s <<= 1) {
            int a = (t >= s) ? buf[t - s] : 0;
            __syncthreads();
            buf[t] += a;
            __syncthreads();
        }
        int carry = carry_s;
        if (i < N_NODES) {
            int excl = carry + buf[t] - v;
            off[i] = excl;
            cnt[i] = excl;
        }
        __syncthreads();
        if (t == 1023) carry_s = carry + buf[1023];
        __syncthreads();
    }
    if (t == 0) off[N_NODES] = carry_s;
}
__global__ __launch_bounds__(256) void k_csr(const int* __restrict__ ei,
                                             int* __restrict__ cursor,
                                             int* __restrict__ csr,
                                             const int* __restrict__ flags) {
    int e = blockIdx.x * 256 + threadIdx.x;
    if (e >= N_EDGES) return;
    int src, dst; load_edge(ei, flags[0], e, src, dst);
    if ((u32)src < N_NODES && (u32)dst < N_NODES) {
        int pos = atomicAdd(&cursor[dst], 1);
        if ((u32)pos < N_EDGES) csr[pos] = src;
    }
}
__device__ inline void agg_bf16(const u16* __restrict__ feat,
                                const int* __restrict__ off, const int* __restrict__ csr,
                                u16* tile, int rb, int wid, int lane) {
    const u32* f32p = (const u32*)feat;
    for (int rr = 0; rr < 32; rr++) {
        int lr = wid * 32 + rr;
        int node = rb + lr;
        float s0 = 0.f, s1 = 0.f;
        int deg = 0;
        if (node < N_NODES) {
            int s = off[node], e = off[node + 1];
            if (s < 0) s = 0;
            if (e > N_EDGES) e = N_EDGES;
            if (e < s) e = s;
            deg = e - s;
            for (int p = s; p < e; p++) {
                int nb = csr[p];
                if ((u32)nb >= N_NODES) nb = 0;
                u32 u = f32p[(size_t)nb * 64 + lane];
                s0 += b2f_lo(u); s1 += b2f_hi(u);
            }
        }
        float sc = deg > 0 ? 1.f / (float)deg : 0.f;
        u16 h0 = f2b(s0 * sc), h1 = f2b(s1 * sc);
        ((u32*)tile)[lr * (TPITCH / 2) + lane] = (u32)h0 | ((u32)h1 << 16);
    }
}
__device__ inline void agg_f32(const float* __restrict__ feat,
                               const int* __restrict__ off, const int* __restrict__ csr,
                               u16* tile, int rb, int wid, int lane) {
    const float2* fp = (const float2*)feat;
    for (int rr = 0; rr < 32; rr++) {
        int lr = wid * 32 + rr;
        int node = rb + lr;
        float s0 = 0.f, s1 = 0.f;
        int deg = 0;
        if (node < N_NODES) {
            int s = off[node], e = off[node + 1];
            if (s < 0) s = 0;
            if (e > N_EDGES) e = N_EDGES;
            if (e < s) e = s;
            deg = e - s;
            for (int p = s; p < e; p++) {
                int nb = csr[p];
                if ((u32)nb >= N_NODES) nb = 0;
                float2 v = fp[(size_t)nb * 64 + lane];
                s0 += v.x; s1 += v.y;
            }
        }
        float sc = deg > 0 ? 1.f / (float)deg : 0.f;
        u16 h0 = f2b(s0 * sc), h1 = f2b(s1 * sc);
        ((u32*)tile)[lr * (TPITCH / 2) + lane] = (u32)h0 | ((u32)h1 << 16);
    }
}
__global__ __launch_bounds__(256) void k_conv1(
    const void* __restrict__ x, const int* __restrict__ off, const int* __restrict__ csr,
    const u16* __restrict__ Wc, const int* __restrict__ flags,
    u16* __restrict__ h1) {
    __shared__ __align__(16) u16 tile[128 * TPITCH];
    int wid = threadIdx.x >> 6, lane = threadIdx.x & 63;
    int r15 = lane & 15, quad = lane >> 4;
    int rb = blockIdx.x * 128;
    int isf = flags[1];
    if (isf) agg_f32((const float*)x, off, csr, tile, rb, wid, lane);
    else     agg_bf16((const u16*)x, off, csr, tile, rb, wid, lane);
    __syncthreads();
    int ar0l = wid * 32 + r15, ar1l = ar0l + 16;
    int ar0g = rb + ar0l; if (ar0g > N_NODES - 1) ar0g = N_NODES - 1;
    int ar1g = rb + ar1l; if (ar1g > N_NODES - 1) ar1g = N_NODES - 1;
    bf16x8 ax0[4], ax1[4];
    if (isf) {
#pragma unroll
        for (int ks = 0; ks < 4; ks++) {
            int ko = ks * 32 + quad * 8;
            ax0[ks] = ldfrag_f32((const float*)x, ar0g, ko);
            ax1[ks] = ldfrag_f32((const float*)x, ar1g, ko);
        }
    } else {
#pragma unroll
        for (int ks = 0; ks < 4; ks++) {
            int ko = ks * 32 + quad * 8;
            ax0[ks] = ldfrag((const u16*)x, ar0g, ko);
            ax1[ks] = ldfrag((const u16*)x, ar1g, ko);
        }
    }
    f32x4 acc[2][8] = {};
#pragma unroll
    for (int ks = 0; ks < 4; ks++) {
        int ko = ks * 32 + quad * 8;
        bf16x8 a0t = ldfrag_lds(tile, ar0l, ko);
        bf16x8 a1t = ldfrag_lds(tile, ar1l, ko);
#pragma unroll
        for (int ct = 0; ct < 8; ct++) {
            bf16x8 bl = ldfrag(Wc + W_W1L, ct * 16 + r15, ko);
            bf16x8 br = ldfrag(Wc + W_W1R, ct * 16 + r15, ko);
            acc[0][ct] = mfma16(a0t, bl, acc[0][ct]);
            acc[0][ct] = mfma16(ax0[ks], br, acc[0][ct]);
            acc[1][ct] = mfma16(a1t, bl, acc[1][ct]);
            acc[1][ct] = mfma16(ax1[ks], br, acc[1][ct]);
        }
    }
#pragma unroll
    for (int ct = 0; ct < 8; ct++) {
        int col = ct * 16 + r15;
        float bb = b2f(Wc[W_B1 + col]);
#pragma unroll
        for (int rt = 0; rt < 2; rt++) {
#pragma unroll
            for (int r = 0; r < 4; r++) {
                int row = rb + wid * 32 + rt * 16 + quad * 4 + r;
                if (row < N_NODES)
                    h1[(size_t)row * 128 + col] = f2b(fmaxf(acc[rt][ct][r] + bb, 0.f));
            }
        }
    }
}
__global__ __launch_bounds__(256) void k_conv2mlp(
    const u16* __restrict__ h1, const int* __restrict__ off, const int* __restrict__ csr,
    const u16* __restrict__ Wc, const int* __restrict__ flags,
    void* __restrict__ out) {
    __shared__ __align__(16) u16 tile[128 * TPITCH];
    int wid = threadIdx.x >> 6, lane = threadIdx.x & 63;
    int r15 = lane & 15, quad = lane >> 4;
    int rb = blockIdx.x * 128;
    agg_bf16(h1, off, csr, tile, rb, wid, lane);
    __syncthreads();
    int ar0l = wid * 32 + r15, ar1l = ar0l + 16;
    int ar0g = rb + ar0l; if (ar0g > N_NODES - 1) ar0g = N_NODES - 1;
    int ar1g = rb + ar1l; if (ar1g > N_NODES - 1) ar1g = N_NODES - 1;
    f32x4 acc2[2][8] = {};
#pragma unroll
    for (int ks = 0; ks < 4; ks++) {
        int ko = ks * 32 + quad * 8;
        bf16x8 a0t = ldfrag_lds(tile, ar0l, ko);
        bf16x8 a1t = ldfrag_lds(tile, ar1l, ko);
        bf16x8 a0s = ldfrag(h1, ar0g, ko);
        bf16x8 a1s = ldfrag(h1, ar1g, ko);
#pragma unroll
        for (int ct = 0; ct < 8; ct++) {
            bf16x8 bl = ldfrag(Wc + W_W2L, ct * 16 + r15, ko);
            bf16x8 br = ldfrag(Wc + W_W2R, ct * 16 + r15, ko);
            acc2[0][ct] = mfma16(a0t, bl, acc2[0][ct]);
            acc2[0][ct] = mfma16(a0s, br, acc2[0][ct]);
            acc2[1][ct] = mfma16(a1t, bl, acc2[1][ct]);
            acc2[1][ct] = mfma16(a1s, br, acc2[1][ct]);
        }
    }
    __syncthreads();
#pragma unroll
    for (int ct = 0; ct < 8; ct++) {
        int col = ct * 16 + r15;
        float bb = b2f(Wc[W_B2 + col]);
#pragma unroll
        for (int rt = 0; rt < 2; rt++) {
#pragma unroll
            for (int r = 0; r < 4; r++) {
                int lr = wid * 32 + rt * 16 + quad * 4 + r;
                tile[lr * TPITCH + col] = f2b(acc2[rt][ct][r] + bb);
            }
        }
    }
    __syncthreads();
    float pr[2][4] = {};
    float b4f = b2f(Wc[W_B4]);
#pragma unroll
    for (int half = 0; half < 2; half++) {
        f32x4 acc3[2][8] = {};
#pragma unroll
        for (int ks = 0; ks < 4; ks++) {
            int ko = ks * 32 + quad * 8;
            bf16x8 a0 = ldfrag_lds(tile, ar0l, ko);
            bf16x8 a1 = ldfrag_lds(tile, ar1l, ko);
#pragma unroll
            for (int ct = 0; ct < 8; ct++) {
                bf16x8 b = ldfrag(Wc + W_W3, half * 128 + ct * 16 + r15, ko);
                acc3[0][ct] = mfma16(a0, b, acc3[0][ct]);
                acc3[1][ct] = mfma16(a1, b, acc3[1][ct]);
            }
        }
#pragma unroll
        for (int ct = 0; ct < 8; ct++) {
            int col = half * 128 + ct * 16 + r15;
            float bb = b2f(Wc[W_B3 + col]);
            float w4 = b2f(Wc[W_W4 + col]);
#pragma unroll
            for (int rt = 0; rt < 2; rt++)
#pragma unroll
                for (int r = 0; r < 4; r++)
                    pr[rt][r] += fmaxf(acc3[rt][ct][r] + bb, 0.f) * w4;
        }
    }
#pragma unroll
    for (int m = 1; m < 16; m <<= 1)
#pragma unroll
        for (int rt = 0; rt < 2; rt++)
#pragma unroll
            for (int r = 0; r < 4; r++)
                pr[rt][r] += __shfl_xor(pr[rt][r], m, 64);
    if (r15 == 0) {
        int isf = flags[1];
#pragma unroll
        for (int rt = 0; rt < 2; rt++) {
#pragma unroll
            for (int r = 0; r < 4; r++) {
                int row = rb + wid * 32 + rt * 16 + quad * 4 + r;
                if (row < N_NODES) {
                    float v = pr[rt][r] + b4f;
                    if (isf) ((float*)out)[row] = v;
                    else     ((u16*)out)[row] = f2b(v);
                }
            }
        }
    }
}

extern "C" void kernel_launch(void* const* d_in, const int* in_sizes, int n_in,
                              void* d_out, int out_size, void* d_ws, size_t ws_size,
                              hipStream_t stream) {
    const void* x  = d_in[0];
    const int* ei  = (const int*)d_in[1];

    const size_t A = 256;
    const size_t sFlg  = 256;
    const size_t sGcur = 1024;
    const size_t sGh   = (((size_t)NBIN * NPART * 4) + A - 1) & ~(A - 1);
    const size_t sCnt  = (((size_t)N_NODES * 4) + A - 1) & ~(A - 1);
    const size_t sOffN = (((size_t)N_NODES * 4) + A - 1) & ~(A - 1);
    const size_t sWc   = ((WTOT * 2) + A - 1) & ~(A - 1);
    const size_t sCsrB = (((size_t)NBIN * BCAP * 4) + A - 1) & ~(A - 1);
    const size_t sFB   = (((size_t)N_NODES * 128 * 2) + A - 1) & ~(A - 1);
    const size_t sOff  = (((size_t)(N_NODES + 1) * 4) + A - 1) & ~(A - 1);
    const size_t sCsr  = (((size_t)N_EDGES * 4) + A - 1) & ~(A - 1);
    const size_t needB1 = sFlg + sGcur + 2 * sGh + sCnt + sOffN + sWc + sCsrB + 2 * sFB;
    const size_t needB0 = needB1 + sFB;
    const size_t needS  = sFlg + sCnt + sOff + sCsr + sFB;

    char* ws = (char*)d_ws;
    int gconv = (N_NODES + 63) / 64;
    int gagg  = (N_NODES + 3) / 4;

    CvtArgs ca;
    const int srcIdx[10] = {2, 4, 5, 7, 8, 10, 3, 6, 9, 11};
    const int offs[10] = {W_W1L, W_W1R, W_W2L, W_W2R, W_W3, W_W4, W_B1, W_B2, W_B3, W_B4};
    const int ns[10]   = {16384, 16384, 16384, 16384, 32768, 256, 128, 128, 256, 1};
    for (int i = 0; i < 10; i++) { ca.src[i] = d_in[srcIdx[i]]; ca.off[i] = offs[i]; ca.n[i] = ns[i]; }

    if (ws_size >= needB1) {
        bool t0 = ws_size >= needB0;
        int* flags = (int*)ws;
        int* gcur  = (int*)(ws + sFlg);
        int* ghist = (int*)(ws + sFlg + sGcur);
        int* gbase = (int*)(ws + sFlg + sGcur + sGh);
        int* cnt   = (int*)(ws + sFlg + sGcur + 2 * sGh);
        int* offN  = (int*)(ws + sFlg + sGcur + 2 * sGh + sCnt);
        u16* Wc    = (u16*)(ws + sFlg + sGcur + 2 * sGh + sCnt + sOffN);
        u32* csrb  = (u32*)(ws + sFlg + sGcur + 2 * sGh + sCnt + sOffN + sWc);
        u16* B1    = (u16*)(ws + sFlg + sGcur + 2 * sGh + sCnt + sOffN + sWc + sCsrB);
        u16* B2    = B1 + (sFB / 2);
        u32* gbuf  = (u32*)B2;         // dead after k_binB
        u16* xb    = B2 + (sFB / 2);   // T0 only

        hipMemsetAsync(ws, 0, sFlg, stream);
        k_detects<<<2, 256, 0, stream>>>((const u64*)ei, (const u32*)x, flags);
        k_rhist<<<NPART, 256, 0, stream>>>(ei, ghist, flags);
        k_rscan<<<NBIN, 512, 0, stream>>>(ghist, gbase, gcur);
        k_rscatter<<<NPART, 256, 0, stream>>>(ei, gbase, gbuf, flags);
        k_binB<<<NBIN, 512, 0, stream>>>(gcur, gbuf, csrb, cnt, offN);
        k_cvtw<<<(WTOT + 255) / 256, 256, 0, stream>>>(ca, Wc, flags);

        if (t0) {
            k_cvtx<<<((N_NODES * 128 / 4) + 255) / 256, 256, 0, stream>>>(x, xb, flags);
            k_aggc<<<gagg, 256, 0, stream>>>(xb, cnt, offN, csrb, B1);
            k_conv1f<false><<<gconv, 256, 0, stream>>>(B1, xb, Wc, flags, B2);
        } else {
            k_aggcx<<<gagg, 256, 0, stream>>>(x, cnt, offN, csrb, flags, B1);
            k_conv1f<true><<<gconv, 256, 0, stream>>>(B1, x, Wc, flags, B2);
        }
        k_aggc<<<gagg, 256, 0, stream>>>(B2, cnt, offN, csrb, B1);
        k_conv2f<<<gconv, 256, 0, stream>>>(B1, B2, Wc, flags, d_out);
    } else if (ws_size >= needS) {
        int* flags = (int*)ws;
        int* cnt   = (int*)(ws + sFlg);
        u16* Wc    = (u16*)(ws + sFlg);
        int* off   = (int*)(ws + sFlg + sCnt);
        int* csr   = (int*)(ws + sFlg + sCnt + sOff);
        u16* h1    = (u16*)(ws + sFlg + sCnt + sOff + sCsr);

        hipMemsetAsync(ws, 0, sFlg + (size_t)N_NODES * 4, stream);
        k_detects<<<2, 256, 0, stream>>>((const u64*)ei, (const u32*)x, flags);
        k_hist<<<N_EDGES / 256, 256, 0, stream>>>(ei, cnt, flags);
        k_scan<<<1, 1024, 0, stream>>>(cnt, off);
        k_csr<<<N_EDGES / 256, 256, 0, stream>>>(ei, cnt, csr, flags);
        k_cvtw<<<(WTOT + 255) / 256, 256, 0, stream>>>(ca, Wc, flags);
        k_conv1<<<(N_NODES + 127) / 128, 256, 0, stream>>>(x, off, csr, Wc, flags, h1);
        k_conv2mlp<<<(N_NODES + 127) / 128, 256, 0, stream>>>(h1, off, csr, Wc, flags, d_out);
    } else {
        k_diag<<<(N_NODES + 255) / 256, 256, 0, stream>>>(
            (u16*)d_out, 2000.0f + (float)(ws_size >> 20));
    }
}